// Round 3
// baseline (1017.698 us; speedup 1.0000x reference)
//
#include <hip/hip_runtime.h>

// MHA forward, round 5: barrier-free MFMA kernels — all operands are L2-resident,
// so MFMA fragments are loaded DIRECTLY from global (per-lane dwordx4), no LDS,
// no __syncthreads, compiler counted-vmcnt pipelining + TLP.
// d_out = [out fp32 (2*2048*1024)] ++ [attn fp32 (2*16*2048*2048)]
// d_ws (ushort units): qb,kb,vb | wqT,wkT,wvT,woT | Qp,Kp,Vt | ctxb

#define D_MODEL 1024
#define NH      16
#define DK      64
#define BATCH   2
#define SEQ     2048
#define MTOT    (BATCH * SEQ)   // 4096

typedef __attribute__((ext_vector_type(8))) short bf16x8;
typedef __attribute__((ext_vector_type(4))) float f32x4;

__device__ __forceinline__ unsigned short f2bf(float f) {
    unsigned u = __float_as_uint(f);
    u += 0x7fff + ((u >> 16) & 1);          // RTN-even
    return (unsigned short)(u >> 16);
}
__device__ __forceinline__ unsigned pk2(float a, float b) {
    return (unsigned)f2bf(a) | ((unsigned)f2bf(b) << 16);
}

// ---------------------------------------------------------------------------
// cast fp32 -> bf16 for q,k,v in one launch. grid (n4/256, 3).
// ---------------------------------------------------------------------------
__global__ __launch_bounds__(256)
void cast3_f32_bf16(const float* __restrict__ q, const float* __restrict__ k,
                    const float* __restrict__ v, unsigned short* __restrict__ dst, int n4)
{
    const float* src = blockIdx.y == 0 ? q : blockIdx.y == 1 ? k : v;
    unsigned short* d = dst + (size_t)blockIdx.y * ((size_t)n4 * 4);
    int i = blockIdx.x * 256 + threadIdx.x;
    if (i < n4) {
        float4 t = ((const float4*)src)[i];
        uint2 w;
        w.x = pk2(t.x, t.y);
        w.y = pk2(t.z, t.w);
        ((uint2*)d)[i] = w;
    }
}

// ---------------------------------------------------------------------------
// transpose+cast weights: W[K][N] fp32 -> Wt[N][K] bf16. grid (32,32,4), 256 thr.
// ---------------------------------------------------------------------------
__global__ __launch_bounds__(256)
void transpose_cast_w(const float* __restrict__ w0, const float* __restrict__ w1,
                      const float* __restrict__ w2, const float* __restrict__ w3,
                      unsigned short* __restrict__ dst)
{
    const float* W = blockIdx.z == 0 ? w0 : blockIdx.z == 1 ? w1 : blockIdx.z == 2 ? w2 : w3;
    unsigned short* Wt = dst + (size_t)blockIdx.z * (D_MODEL * D_MODEL);
    __shared__ float t[32][33];
    const int tx = threadIdx.x & 31, ty = threadIdx.x >> 5;   // 32 x 8
    const int k0 = blockIdx.x * 32, n0 = blockIdx.y * 32;
#pragma unroll
    for (int r = 0; r < 4; ++r)
        t[ty + r * 8][tx] = W[(size_t)(k0 + ty + r * 8) * D_MODEL + n0 + tx];
    __syncthreads();
#pragma unroll
    for (int r = 0; r < 4; ++r)
        Wt[(size_t)(n0 + ty + r * 8) * D_MODEL + k0 + tx] = f2bf(t[tx][ty + r * 8]);
}

// ---------------------------------------------------------------------------
// bf16 MFMA GEMM, 128x128 tile, BK=32, 4 waves, NO LDS: fragments loaded
// straight from global (A panels / Wt slab are L2-resident). One-deep manual
// fragment prefetch; zero barriers.
// mode 0: z=0/1 -> bf16 split-head (B,NH,SEQ,DK); z=2 -> transposed (B,NH,DK,SEQ).
// mode 1: fp32 row-major.
// ---------------------------------------------------------------------------
__global__ __launch_bounds__(256)
void gemm_mfma(const unsigned short* __restrict__ A0, const unsigned short* __restrict__ A1,
               const unsigned short* __restrict__ A2, const unsigned short* __restrict__ WT,
               const float* __restrict__ b0, const float* __restrict__ b1,
               const float* __restrict__ b2,
               unsigned short* __restrict__ D0, unsigned short* __restrict__ D1,
               unsigned short* __restrict__ D2, float* __restrict__ Dout, int mode)
{
    const int K = D_MODEL;
    const int z = blockIdx.z;
    const unsigned short* A = (mode == 0) ? (z == 0 ? A0 : z == 1 ? A1 : A2) : A0;
    const unsigned short* Wt = (mode == 0) ? WT + (size_t)z * (D_MODEL * D_MODEL) : WT;
    const float* bias = (z == 0 ? b0 : z == 1 ? b1 : b2);

    const int tid = threadIdx.x;
    const int wave = tid >> 6, lane = tid & 63;
    const int quad = lane >> 4, l15 = lane & 15;
    const int m0 = blockIdx.x * 128, n0 = blockIdx.y * 128;
    const int wm = (wave & 1) * 64, wn = (wave >> 1) * 64;

    // fragment bases: lane (l15,quad) reads row (.. + i*16 + l15), elems quad*8..+7
    const unsigned short* Abase = A  + (size_t)(m0 + wm + l15) * K + quad * 8;
    const unsigned short* Bbase = Wt + (size_t)(n0 + wn + l15) * K + quad * 8;

    f32x4 acc[4][4];
#pragma unroll
    for (int i = 0; i < 4; ++i)
#pragma unroll
        for (int j = 0; j < 4; ++j) acc[i][j] = (f32x4){0.f, 0.f, 0.f, 0.f};

    bf16x8 a[4], b[4];
#pragma unroll
    for (int i = 0; i < 4; ++i) {
        a[i] = *(const bf16x8*)(Abase + (size_t)i * 16 * K);
        b[i] = *(const bf16x8*)(Bbase + (size_t)i * 16 * K);
    }

    for (int k0 = 0; k0 < K; k0 += 32) {
        bf16x8 an[4], bn[4];
        const bool more = (k0 + 32) < K;
        if (more) {
#pragma unroll
            for (int i = 0; i < 4; ++i) {
                an[i] = *(const bf16x8*)(Abase + (size_t)i * 16 * K + k0 + 32);
                bn[i] = *(const bf16x8*)(Bbase + (size_t)i * 16 * K + k0 + 32);
            }
        }
#pragma unroll
        for (int i = 0; i < 4; ++i)
#pragma unroll
            for (int j = 0; j < 4; ++j)
                acc[i][j] = __builtin_amdgcn_mfma_f32_16x16x32_bf16(a[i], b[j], acc[i][j], 0, 0, 0);
        if (more) {
#pragma unroll
            for (int i = 0; i < 4; ++i) { a[i] = an[i]; b[i] = bn[i]; }
        }
    }

    unsigned short* Dh = (z == 0 ? D0 : z == 1 ? D1 : D2);
#pragma unroll
    for (int j = 0; j < 4; ++j) {
        const int col = n0 + wn + j * 16 + l15;
        const float bv = bias[col];
        const int h = col >> 6, d = col & 63;
#pragma unroll
        for (int i = 0; i < 4; ++i) {
            const int row0 = m0 + wm + i * 16 + quad * 4;
            if (mode == 0 && z == 2) {
                const int bb = row0 >> 11, ss = row0 & (SEQ - 1);
                uint2 w2;
                w2.x = pk2(acc[i][j][0] + bv, acc[i][j][1] + bv);
                w2.y = pk2(acc[i][j][2] + bv, acc[i][j][3] + bv);
                *(uint2*)&Dh[(((size_t)bb * NH + h) * DK + d) * SEQ + ss] = w2;
            } else {
#pragma unroll
                for (int r = 0; r < 4; ++r) {
                    const int row = row0 + r;
                    const float val = acc[i][j][r] + bv;
                    if (mode == 0) {
                        const int bb = row >> 11, ss = row & (SEQ - 1);
                        Dh[(((size_t)bb * NH + h) * SEQ + ss) * DK + d] = f2bf(val);
                    } else {
                        Dout[(size_t)row * D_MODEL + col] = val;
                    }
                }
            }
        }
    }
}

// ---------------------------------------------------------------------------
// MFMA causal attention, round 5: NO LDS, NO barriers. K/V fragments loaded
// per-lane directly from global (L2-resident per head). Swapped-operand QK^T;
// in-register shfl P exchange (verified round 4). grid (SEQ/64, B*NH), 256 thr.
// ---------------------------------------------------------------------------
__global__ __launch_bounds__(256)
void attn_fused(const unsigned short* __restrict__ Qp, const unsigned short* __restrict__ Kp,
                const unsigned short* __restrict__ Vtp, float* __restrict__ attn,
                unsigned short* __restrict__ ctxb)
{
    const int tid  = threadIdx.x;
    const int w    = tid >> 6;
    const int lane = tid & 63;
    const int l15  = lane & 15;
    const int hi   = lane >> 4;
    const int qt   = blockIdx.x;
    const int bh   = blockIdx.y;
    const int q0   = qt * 64;

    const unsigned short* Qh = Qp  + (size_t)bh * SEQ * DK;
    const unsigned short* Kh = Kp  + (size_t)bh * SEQ * DK;
    const unsigned short* Vh = Vtp + (size_t)bh * DK * SEQ;   // [d][s]
    float* attn_h = attn + (size_t)bh * SEQ * SEQ;
    const int bb = bh >> 4, hh = bh & 15;
    unsigned short* ctx_h = ctxb + (size_t)bb * SEQ * D_MODEL + hh * DK;

    // Q fragments in registers: lane holds Q[q][k=hi*8..+7] / [32+hi*8..+7]
    const int qrow = q0 + w * 16 + l15;
    const bf16x8 qf0 = *(const bf16x8*)(Qh + (size_t)qrow * DK + hi * 8);
    const bf16x8 qf1 = *(const bf16x8*)(Qh + (size_t)qrow * DK + 32 + hi * 8);

    // fragment bases: K row (kt*64+kk*16+l15), elems hi*8 / 32+hi*8
    //                 V row (jt*16+l15) of [d][s], keys kt*64+hi*8 / +32+hi*8
    const unsigned short* Kfb = Kh + (size_t)l15 * DK + hi * 8;
    const unsigned short* Vfb = Vh + (size_t)l15 * SEQ + hi * 8;

    // ---------------- pass 1: running max + sumexp ----------------
    float run_m = -1e30f, run_l = 0.f;
    for (int kt = 0; kt <= qt; ++kt) {
        const unsigned short* kb = Kfb + (size_t)kt * 64 * DK;
        f32x4 s[4];
#pragma unroll
        for (int kk = 0; kk < 4; ++kk) {
            bf16x8 k0 = *(const bf16x8*)(kb + kk * 16 * DK);
            bf16x8 k1 = *(const bf16x8*)(kb + kk * 16 * DK + 32);
            f32x4 zz = (f32x4){0.f, 0.f, 0.f, 0.f};
            zz = __builtin_amdgcn_mfma_f32_16x16x32_bf16(k0, qf0, zz, 0, 0, 0);
            s[kk] = __builtin_amdgcn_mfma_f32_16x16x32_bf16(k1, qf1, zz, 0, 0, 0);
        }
        float tm = -1e30f;
#pragma unroll
        for (int kk = 0; kk < 4; ++kk)
#pragma unroll
            for (int r = 0; r < 4; ++r) {
                const int key = kt * 64 + kk * 16 + hi * 4 + r;
                const float x = (key <= qrow) ? s[kk][r] * 0.125f : -1e30f;
                s[kk][r] = x;
                tm = fmaxf(tm, x);
            }
        tm = fmaxf(tm, __shfl_xor(tm, 16));
        tm = fmaxf(tm, __shfl_xor(tm, 32));
        const float nm = fmaxf(run_m, tm);
        float sum = 0.f;
#pragma unroll
        for (int kk = 0; kk < 4; ++kk)
#pragma unroll
            for (int r = 0; r < 4; ++r)
                sum += __expf(s[kk][r] - nm);
        sum += __shfl_xor(sum, 16);
        sum += __shfl_xor(sum, 32);
        run_l = run_l * __expf(run_m - nm) + sum;
        run_m = nm;
    }
    const float m_f = run_m;
    const float linv = 1.f / run_l;

    // ---------------- pass 2: write attn, accumulate PV ----------------
    f32x4 acc_pv[4];
#pragma unroll
    for (int jt = 0; jt < 4; ++jt) acc_pv[jt] = (f32x4){0.f, 0.f, 0.f, 0.f};

    const int srcA = l15 + 32 * (hi & 1);
    const int srcB = srcA + 16;
    const bool hiSel = (hi >> 1) != 0;

    for (int kt = 0; kt <= qt; ++kt) {
        // V fragments first: latency covered by QK^T + softmax below
        bf16x8 v0[4], v1[4];
        const unsigned short* vb = Vfb + kt * 64;
#pragma unroll
        for (int jt = 0; jt < 4; ++jt) {
            v0[jt] = *(const bf16x8*)(vb + (size_t)jt * 16 * SEQ);
            v1[jt] = *(const bf16x8*)(vb + (size_t)jt * 16 * SEQ + 32);
        }
        const unsigned short* kb = Kfb + (size_t)kt * 64 * DK;
        f32x4 s[4];
#pragma unroll
        for (int kk = 0; kk < 4; ++kk) {
            bf16x8 k0 = *(const bf16x8*)(kb + kk * 16 * DK);
            bf16x8 k1 = *(const bf16x8*)(kb + kk * 16 * DK + 32);
            f32x4 zz = (f32x4){0.f, 0.f, 0.f, 0.f};
            zz = __builtin_amdgcn_mfma_f32_16x16x32_bf16(k0, qf0, zz, 0, 0, 0);
            s[kk] = __builtin_amdgcn_mfma_f32_16x16x32_bf16(k1, qf1, zz, 0, 0, 0);
        }
        float pv[4][4];
#pragma unroll
        for (int kk = 0; kk < 4; ++kk) {
#pragma unroll
            for (int r = 0; r < 4; ++r) {
                const int key = kt * 64 + kk * 16 + hi * 4 + r;
                pv[kk][r] = (key <= qrow) ? __expf(s[kk][r] * 0.125f - m_f) * linv : 0.f;
            }
            float4 st;
            st.x = pv[kk][0]; st.y = pv[kk][1]; st.z = pv[kk][2]; st.w = pv[kk][3];
            *(float4*)&attn_h[(size_t)qrow * SEQ + kt * 64 + kk * 16 + hi * 4] = st;
        }
        // pack P to bf16 pairs: D[kk][h] = {key 16kk+4hi+2h, +1}
        unsigned D00 = pk2(pv[0][0], pv[0][1]), D01 = pk2(pv[0][2], pv[0][3]);
        unsigned D10 = pk2(pv[1][0], pv[1][1]), D11 = pk2(pv[1][2], pv[1][3]);
        unsigned D20 = pk2(pv[2][0], pv[2][1]), D21 = pk2(pv[2][2], pv[2][3]);
        unsigned D30 = pk2(pv[3][0], pv[3][1]), D31 = pk2(pv[3][2], pv[3][3]);
        // in-register exchange: dest lane (l15,quad) gathers keys quad*8..+7
        unsigned a00 = __shfl((int)D00, srcA), a10 = __shfl((int)D10, srcA);
        unsigned a01 = __shfl((int)D01, srcA), a11 = __shfl((int)D11, srcA);
        unsigned b00 = __shfl((int)D00, srcB), b10 = __shfl((int)D10, srcB);
        unsigned b01 = __shfl((int)D01, srcB), b11 = __shfl((int)D11, srcB);
        unsigned a20 = __shfl((int)D20, srcA), a30 = __shfl((int)D30, srcA);
        unsigned a21 = __shfl((int)D21, srcA), a31 = __shfl((int)D31, srcA);
        unsigned b20 = __shfl((int)D20, srcB), b30 = __shfl((int)D30, srcB);
        unsigned b21 = __shfl((int)D21, srcB), b31 = __shfl((int)D31, srcB);
        uint4 u0, u1;
        u0.x = hiSel ? a10 : a00;  u0.y = hiSel ? a11 : a01;
        u0.z = hiSel ? b10 : b00;  u0.w = hiSel ? b11 : b01;
        u1.x = hiSel ? a30 : a20;  u1.y = hiSel ? a31 : a21;
        u1.z = hiSel ? b30 : b20;  u1.w = hiSel ? b31 : b21;
        bf16x8 pa0 = *(bf16x8*)&u0;
        bf16x8 pa1 = *(bf16x8*)&u1;
#pragma unroll
        for (int jt = 0; jt < 4; ++jt) {
            acc_pv[jt] = __builtin_amdgcn_mfma_f32_16x16x32_bf16(pa0, v0[jt], acc_pv[jt], 0, 0, 0);
            acc_pv[jt] = __builtin_amdgcn_mfma_f32_16x16x32_bf16(pa1, v1[jt], acc_pv[jt], 0, 0, 0);
        }
    }

    // zero-fill the masked upper tiles of attn
    const float4 zf = make_float4(0.f, 0.f, 0.f, 0.f);
    for (int kt = qt + 1; kt < SEQ / 64; ++kt) {
#pragma unroll
        for (int kk = 0; kk < 4; ++kk)
            *(float4*)&attn_h[(size_t)qrow * SEQ + kt * 64 + kk * 16 + hi * 4] = zf;
    }

    // ctx write (bf16, B,S,D layout): lane holds ctx[q=w*16+hi*4+r][d=jt*16+l15]
#pragma unroll
    for (int jt = 0; jt < 4; ++jt) {
        const int d = jt * 16 + l15;
#pragma unroll
        for (int r = 0; r < 4; ++r) {
            const int qq = q0 + w * 16 + hi * 4 + r;
            ctx_h[(size_t)qq * D_MODEL + d] = f2bf(acc_pv[jt][r]);
        }
    }
}

// ---------------------------------------------------------------------------
extern "C" void kernel_launch(void* const* d_in, const int* in_sizes, int n_in,
                              void* d_out, int out_size, void* d_ws, size_t ws_size,
                              hipStream_t stream)
{
    const float* q  = (const float*)d_in[0];
    const float* k  = (const float*)d_in[1];
    const float* v  = (const float*)d_in[2];
    const float* wq = (const float*)d_in[4];
    const float* bq = (const float*)d_in[5];
    const float* wk = (const float*)d_in[6];
    const float* bk = (const float*)d_in[7];
    const float* wv = (const float*)d_in[8];
    const float* bv = (const float*)d_in[9];
    const float* wo = (const float*)d_in[10];
    const float* bo = (const float*)d_in[11];

    float* out  = (float*)d_out;
    float* attn = out + (size_t)BATCH * SEQ * D_MODEL;

    const size_t NE = (size_t)MTOT * D_MODEL;     // 4194304
    const size_t WE = (size_t)D_MODEL * D_MODEL;  // 1048576
    unsigned short* ws  = (unsigned short*)d_ws;
    unsigned short* qb  = ws;
    unsigned short* kb  = qb + NE;
    unsigned short* vb  = kb + NE;
    unsigned short* wT  = vb + NE;                // 4 slabs: wq,wk,wv,wo transposed
    unsigned short* Qp  = wT + 4 * WE;            // (B,H,S,64) bf16
    unsigned short* Kp  = Qp + NE;
    unsigned short* Vt  = Kp + NE;                // (B,H,64,S) bf16 (transposed!)
    unsigned short* ctxb = Vt + NE;               // (B,S,D) bf16

    const int n4 = (int)(NE / 4);
    cast3_f32_bf16<<<dim3((n4 + 255) / 256, 3), 256, 0, stream>>>(q, k, v, qb, n4);
    transpose_cast_w<<<dim3(32, 32, 4), 256, 0, stream>>>(wq, wk, wv, wo, wT);

    gemm_mfma<<<dim3(32, 8, 3), 256, 0, stream>>>(qb, kb, vb, wT, bq, bk, bv,
                                                  Qp, Kp, Vt, nullptr, 0);

    dim3 ga(SEQ / 64, BATCH * NH);
    attn_fused<<<ga, 256, 0, stream>>>(Qp, Kp, Vt, attn, ctxb);

    gemm_mfma<<<dim3(32, 8, 1), 256, 0, stream>>>(ctxb, nullptr, nullptr, wT + 3 * WE,
                                                  bo, nullptr, nullptr,
                                                  nullptr, nullptr, nullptr, out, 1);
}

// Round 5
// 771.058 us; speedup vs baseline: 1.3199x; 1.3199x over previous
//
#include <hip/hip_runtime.h>

// MHA forward, round 6 resubmit (round-4 bench was an infra failure, no counters).
// Structure: round-2 LDS/global_load_lds base +
//  - attn: QBLK=128 (2 strips/wave) -> half the stage/barrier cost per query
//  - out-proj GEMM: 128x64 tiles (MODE template) -> 2 blocks/CU instead of 1
// d_out = [out fp32 (2*2048*1024)] ++ [attn fp32 (2*16*2048*2048)]
// d_ws (ushort units): qb,kb,vb | wqT,wkT,wvT,woT | Qp,Kp,Vt | ctxb

#define D_MODEL 1024
#define NH      16
#define DK      64
#define BATCH   2
#define SEQ     2048
#define MTOT    (BATCH * SEQ)   // 4096

typedef __attribute__((ext_vector_type(8))) short bf16x8;
typedef __attribute__((ext_vector_type(4))) float f32x4;

__device__ __forceinline__ unsigned short f2bf(float f) {
    unsigned u = __float_as_uint(f);
    u += 0x7fff + ((u >> 16) & 1);          // RTN-even
    return (unsigned short)(u >> 16);
}
__device__ __forceinline__ unsigned pk2(float a, float b) {
    return (unsigned)f2bf(a) | ((unsigned)f2bf(b) << 16);
}

__device__ __forceinline__ void async_ld16(void* lds, const void* g) {
    __builtin_amdgcn_global_load_lds(
        (const __attribute__((address_space(1))) void*)g,
        (__attribute__((address_space(3))) void*)lds, 16, 0, 0);
}

// ---------------------------------------------------------------------------
// cast fp32 -> bf16 for q,k,v in one launch. grid (n4/256, 3).
// ---------------------------------------------------------------------------
__global__ __launch_bounds__(256)
void cast3_f32_bf16(const float* __restrict__ q, const float* __restrict__ k,
                    const float* __restrict__ v, unsigned short* __restrict__ dst, int n4)
{
    const float* src = blockIdx.y == 0 ? q : blockIdx.y == 1 ? k : v;
    unsigned short* d = dst + (size_t)blockIdx.y * ((size_t)n4 * 4);
    int i = blockIdx.x * 256 + threadIdx.x;
    if (i < n4) {
        float4 t = ((const float4*)src)[i];
        uint2 w;
        w.x = pk2(t.x, t.y);
        w.y = pk2(t.z, t.w);
        ((uint2*)d)[i] = w;
    }
}

// ---------------------------------------------------------------------------
// transpose+cast weights: W[K][N] fp32 -> Wt[N][K] bf16. grid (32,32,4), 256 thr.
// ---------------------------------------------------------------------------
__global__ __launch_bounds__(256)
void transpose_cast_w(const float* __restrict__ w0, const float* __restrict__ w1,
                      const float* __restrict__ w2, const float* __restrict__ w3,
                      unsigned short* __restrict__ dst)
{
    const float* W = blockIdx.z == 0 ? w0 : blockIdx.z == 1 ? w1 : blockIdx.z == 2 ? w2 : w3;
    unsigned short* Wt = dst + (size_t)blockIdx.z * (D_MODEL * D_MODEL);
    __shared__ float t[32][33];
    const int tx = threadIdx.x & 31, ty = threadIdx.x >> 5;   // 32 x 8
    const int k0 = blockIdx.x * 32, n0 = blockIdx.y * 32;
#pragma unroll
    for (int r = 0; r < 4; ++r)
        t[ty + r * 8][tx] = W[(size_t)(k0 + ty + r * 8) * D_MODEL + n0 + tx];
    __syncthreads();
#pragma unroll
    for (int r = 0; r < 4; ++r)
        Wt[(size_t)(n0 + ty + r * 8) * D_MODEL + k0 + tx] = f2bf(t[tx][ty + r * 8]);
}

// ---------------------------------------------------------------------------
// bf16 MFMA GEMM, BK=32, 4 waves, 2-phase prefetch double-buffer, XOR-swizzled
// LDS (chunk ^= (row>>1)&3, both-sides via pre-swizzled source).
// MODE 0: 128x128 tile; z=0/1 -> bf16 split-head (B,NH,SEQ,DK); z=2 ->
//         transposed (B,NH,DK,SEQ).
// MODE 1: 128x64 tile (waves 2x2 over 64x32) -> 512 blocks = 2/CU; fp32 out.
// ---------------------------------------------------------------------------
template<int MODE>
__global__ __launch_bounds__(256)
void gemm_mfma(const unsigned short* __restrict__ A0, const unsigned short* __restrict__ A1,
               const unsigned short* __restrict__ A2, const unsigned short* __restrict__ WT,
               const float* __restrict__ b0, const float* __restrict__ b1,
               const float* __restrict__ b2,
               unsigned short* __restrict__ D0, unsigned short* __restrict__ D1,
               unsigned short* __restrict__ D2, float* __restrict__ Dout)
{
    const int K = D_MODEL;
    constexpr int NJ = (MODE == 1) ? 2 : 4;              // B fragments per wave
    constexpr int BNROWS = (MODE == 1) ? 64 : 128;       // B tile rows
    __shared__ unsigned short As[2][128 * 32];           // [m][k], chunk-swizzled
    __shared__ unsigned short Bs[2][BNROWS * 32];        // [n][k], chunk-swizzled

    const int z = blockIdx.z;
    const unsigned short* A = (MODE == 0) ? (z == 0 ? A0 : z == 1 ? A1 : A2) : A0;
    const unsigned short* Wt = (MODE == 0) ? WT + (size_t)z * (D_MODEL * D_MODEL) : WT;
    const float* bias = (z == 0 ? b0 : z == 1 ? b1 : b2);

    const int tid = threadIdx.x;
    const int wave = tid >> 6, lane = tid & 63;
    const int quad = lane >> 4, l15 = lane & 15;
    const int m0 = blockIdx.x * 128;
    const int n0 = blockIdx.y * ((MODE == 1) ? 64 : 128);
    const int wm = (wave & 1) * 64;
    const int wn = (MODE == 1) ? (wave >> 1) * 32 : (wave >> 1) * 64;

    // staging: lane writes phys chunk (lane&3) of row srow; source is logical
    // chunk (lane&3) ^ ((srow>>1)&3)  (involution; read side applies same XOR)
    const int srow = (lane >> 2);
    const int skel = (((lane & 3) ^ ((srow >> 1) & 3)) * 8);
    const unsigned short* gA0 = A  + (size_t)(m0 + wave * 32 +      srow) * K + skel;
    const unsigned short* gA1 = A  + (size_t)(m0 + wave * 32 + 16 + srow) * K + skel;
    const unsigned short* gB0 = Wt + (size_t)(n0 + wave * ((MODE == 1) ? 16 : 32) + srow) * K + skel;
    const unsigned short* gB1 = Wt + (size_t)(n0 + wave * 32 + 16 + srow) * K + skel;  // MODE 0 only

    f32x4 acc[4][NJ];
#pragma unroll
    for (int i = 0; i < 4; ++i)
#pragma unroll
        for (int j = 0; j < NJ; ++j) acc[i][j] = (f32x4){0.f, 0.f, 0.f, 0.f};

    auto stage = [&](int buf, int k0) {
        async_ld16(&As[buf][(wave * 2 + 0) * 512], gA0 + k0);
        async_ld16(&As[buf][(wave * 2 + 1) * 512], gA1 + k0);
        if (MODE == 1) {
            async_ld16(&Bs[buf][wave * 512], gB0 + k0);
        } else {
            async_ld16(&Bs[buf][(wave * 2 + 0) * 512], gB0 + k0);
            async_ld16(&Bs[buf][(wave * 2 + 1) * 512], gB1 + k0);
        }
    };

    stage(0, 0);
    __syncthreads();
    int cur = 0;
    const int rsw = (l15 >> 1) & 3;   // read-side chunk XOR key (row>>1)&3

    for (int k0 = 0; k0 < K; k0 += 32) {
        if (k0 + 32 < K) stage(cur ^ 1, k0 + 32);   // issue BEFORE compute (T3)
        bf16x8 a[4], b[NJ];
#pragma unroll
        for (int i = 0; i < 4; ++i)
            a[i] = *(const bf16x8*)&As[cur][(wm + i * 16 + l15) * 32 + ((quad ^ rsw) << 3)];
#pragma unroll
        for (int j = 0; j < NJ; ++j)
            b[j] = *(const bf16x8*)&Bs[cur][(wn + j * 16 + l15) * 32 + ((quad ^ rsw) << 3)];
#pragma unroll
        for (int i = 0; i < 4; ++i)
#pragma unroll
            for (int j = 0; j < NJ; ++j)
                acc[i][j] = __builtin_amdgcn_mfma_f32_16x16x32_bf16(a[i], b[j], acc[i][j], 0, 0, 0);
        __syncthreads();   // implicit vmcnt(0): next buffer staged; reads of cur done
        cur ^= 1;
    }

    unsigned short* Dh = (z == 0 ? D0 : z == 1 ? D1 : D2);
#pragma unroll
    for (int j = 0; j < NJ; ++j) {
        const int col = n0 + wn + j * 16 + l15;
        const float bv = bias[col];
        const int h = col >> 6, d = col & 63;
#pragma unroll
        for (int i = 0; i < 4; ++i) {
            const int row0 = m0 + wm + i * 16 + quad * 4;
            if (MODE == 0 && z == 2) {
                const int bb = row0 >> 11, ss = row0 & (SEQ - 1);
                uint2 w2;
                w2.x = pk2(acc[i][j][0] + bv, acc[i][j][1] + bv);
                w2.y = pk2(acc[i][j][2] + bv, acc[i][j][3] + bv);
                *(uint2*)&Dh[(((size_t)bb * NH + h) * DK + d) * SEQ + ss] = w2;
            } else {
#pragma unroll
                for (int r = 0; r < 4; ++r) {
                    const int row = row0 + r;
                    const float val = acc[i][j][r] + bv;
                    if (MODE == 0) {
                        const int bb = row >> 11, ss = row & (SEQ - 1);
                        Dh[(((size_t)bb * NH + h) * SEQ + ss) * DK + d] = f2bf(val);
                    } else {
                        Dout[(size_t)row * D_MODEL + col] = val;
                    }
                }
            }
        }
    }
}

// ---------------------------------------------------------------------------
// MFMA causal attention, QBLK=128: each wave owns TWO 16-row strips (rows
// q0+w*16 and q0+64+w*16), sharing each staged K/V tile -> half the stage/
// barrier cost per query vs round 2. grid = (SEQ/128, B*NH), block = 256.
// Swapped-operand QK^T; dbuf prefetch, 1 barrier/kt; in-register shfl P
// exchange (verified round 2/4).
// ---------------------------------------------------------------------------
__global__ __launch_bounds__(256)
void attn_fused(const unsigned short* __restrict__ Qp, const unsigned short* __restrict__ Kp,
                const unsigned short* __restrict__ Vtp, float* __restrict__ attn,
                unsigned short* __restrict__ ctxb)
{
    __shared__ unsigned short Ks[2][64 * 64];   // [key][d], row-XOR-swizzled
    __shared__ unsigned short Vs[2][64 * 64];   // [d][key], row-XOR-swizzled

    const int tid  = threadIdx.x;
    const int w    = tid >> 6;
    const int lane = tid & 63;
    const int l15  = lane & 15;
    const int hi   = lane >> 4;
    const int bx   = blockIdx.x;
    const int bh   = blockIdx.y;
    const int q0   = bx * 128;
    const int qtb  = 2 * bx + 1;     // last kt tile index for this block

    const unsigned short* Qh = Qp  + (size_t)bh * SEQ * DK;
    const unsigned short* Kh = Kp  + (size_t)bh * SEQ * DK;
    const unsigned short* Vh = Vtp + (size_t)bh * DK * SEQ;   // [d][s]
    float* attn_h = attn + (size_t)bh * SEQ * SEQ;
    const int bb = bh >> 4, hh = bh & 15;
    unsigned short* ctx_h = ctxb + (size_t)bb * SEQ * D_MODEL + hh * DK;

    // staging: wave w stages rows w*16..+15; source pre-swizzled (chunk ^ row&7)
    const int srow = w * 16 + (lane >> 3);
    const int sswz = (lane & 7) ^ (srow & 7);
    const unsigned short* gK0 = Kh + (size_t)srow * DK + sswz * 8;
    const unsigned short* gK1 = Kh + (size_t)(srow + 8) * DK + sswz * 8;
    const unsigned short* gV0 = Vh + (size_t)srow * SEQ + sswz * 8;
    const unsigned short* gV1 = Vh + (size_t)(srow + 8) * SEQ + sswz * 8;

    auto stageK = [&](int buf, int kt) {
        async_ld16(&Ks[buf][w * 1024],       gK0 + (size_t)kt * 64 * DK);
        async_ld16(&Ks[buf][w * 1024 + 512], gK1 + (size_t)kt * 64 * DK);
    };
    auto stageV = [&](int buf, int kt) {
        async_ld16(&Vs[buf][w * 1024],       gV0 + kt * 64);
        async_ld16(&Vs[buf][w * 1024 + 512], gV1 + kt * 64);
    };

    // Q fragments for both strips
    const int qr0 = q0 + w * 16 + l15;        // strip 0
    const int qr1 = qr0 + 64;                 // strip 1
    const bf16x8 qa0 = *(const bf16x8*)(Qh + (size_t)qr0 * DK + hi * 8);
    const bf16x8 qb0 = *(const bf16x8*)(Qh + (size_t)qr0 * DK + 32 + hi * 8);
    const bf16x8 qa1 = *(const bf16x8*)(Qh + (size_t)qr1 * DK + hi * 8);
    const bf16x8 qb1 = *(const bf16x8*)(Qh + (size_t)qr1 * DK + 32 + hi * 8);

    const int swz = (l15 & 7) << 4;   // read-side XOR (row&7 == l15&7 for our rows)

    auto qk_tile = [&](int cur, bf16x8 qa, bf16x8 qb, f32x4* s) {
#pragma unroll
        for (int kk = 0; kk < 4; ++kk) {
            const char* kbp = (const char*)&Ks[cur][0] + (kk * 16 + l15) * 128;
            bf16x8 k0 = *(const bf16x8*)(kbp + ((hi * 16) ^ swz));
            bf16x8 k1 = *(const bf16x8*)(kbp + ((64 + hi * 16) ^ swz));
            f32x4 zz = (f32x4){0.f, 0.f, 0.f, 0.f};
            zz = __builtin_amdgcn_mfma_f32_16x16x32_bf16(k0, qa, zz, 0, 0, 0);
            s[kk] = __builtin_amdgcn_mfma_f32_16x16x32_bf16(k1, qb, zz, 0, 0, 0);
        }
    };
    auto sm_update = [&](f32x4* s, int qrow, int kt, float& rm, float& rl) {
        float tm = -1e30f;
#pragma unroll
        for (int kk = 0; kk < 4; ++kk)
#pragma unroll
            for (int r = 0; r < 4; ++r) {
                const int key = kt * 64 + kk * 16 + hi * 4 + r;
                const float x = (key <= qrow) ? s[kk][r] * 0.125f : -1e30f;
                s[kk][r] = x;
                tm = fmaxf(tm, x);
            }
        tm = fmaxf(tm, __shfl_xor(tm, 16));
        tm = fmaxf(tm, __shfl_xor(tm, 32));
        const float nm = fmaxf(rm, tm);
        float sum = 0.f;
#pragma unroll
        for (int kk = 0; kk < 4; ++kk)
#pragma unroll
            for (int r = 0; r < 4; ++r)
                sum += __expf(s[kk][r] - nm);
        sum += __shfl_xor(sum, 16);
        sum += __shfl_xor(sum, 32);
        rl = rl * __expf(rm - nm) + sum;
        rm = nm;
    };

    // ---------------- pass 1: running max + sumexp (both strips) ----------------
    float run_m[2] = {-1e30f, -1e30f}, run_l[2] = {0.f, 0.f};
    stageK(0, 0);
    __syncthreads();
    int cur = 0;
    for (int kt = 0; kt <= qtb; ++kt) {
        if (kt < qtb) stageK(cur ^ 1, kt + 1);
        f32x4 s[4];
        if (kt < qtb) {                    // strip 0 active for kt <= qtb-1
            qk_tile(cur, qa0, qb0, s);
            sm_update(s, qr0, kt, run_m[0], run_l[0]);
        }
        qk_tile(cur, qa1, qb1, s);         // strip 1 active for all kt
        sm_update(s, qr1, kt, run_m[1], run_l[1]);
        __syncthreads();
        cur ^= 1;
    }
    const float m0f = run_m[0], l0inv = 1.f / run_l[0];
    const float m1f = run_m[1], l1inv = 1.f / run_l[1];

    // ---------------- pass 2: write attn, accumulate PV ----------------
    f32x4 acc0[4], acc1[4];
#pragma unroll
    for (int jt = 0; jt < 4; ++jt) {
        acc0[jt] = (f32x4){0.f, 0.f, 0.f, 0.f};
        acc1[jt] = (f32x4){0.f, 0.f, 0.f, 0.f};
    }

    const int srcA = l15 + 32 * (hi & 1);
    const int srcB = srcA + 16;
    const bool hiSel = (hi >> 1) != 0;

    auto exchange = [&](const float pv[4][4], bf16x8& pa0, bf16x8& pa1) {
        unsigned D00 = pk2(pv[0][0], pv[0][1]), D01 = pk2(pv[0][2], pv[0][3]);
        unsigned D10 = pk2(pv[1][0], pv[1][1]), D11 = pk2(pv[1][2], pv[1][3]);
        unsigned D20 = pk2(pv[2][0], pv[2][1]), D21 = pk2(pv[2][2], pv[2][3]);
        unsigned D30 = pk2(pv[3][0], pv[3][1]), D31 = pk2(pv[3][2], pv[3][3]);
        unsigned a00 = __shfl((int)D00, srcA), a10 = __shfl((int)D10, srcA);
        unsigned a01 = __shfl((int)D01, srcA), a11 = __shfl((int)D11, srcA);
        unsigned b00 = __shfl((int)D00, srcB), b10 = __shfl((int)D10, srcB);
        unsigned b01 = __shfl((int)D01, srcB), b11 = __shfl((int)D11, srcB);
        unsigned a20 = __shfl((int)D20, srcA), a30 = __shfl((int)D30, srcA);
        unsigned a21 = __shfl((int)D21, srcA), a31 = __shfl((int)D31, srcA);
        unsigned b20 = __shfl((int)D20, srcB), b30 = __shfl((int)D30, srcB);
        unsigned b21 = __shfl((int)D21, srcB), b31 = __shfl((int)D31, srcB);
        uint4 u0, u1;
        u0.x = hiSel ? a10 : a00;  u0.y = hiSel ? a11 : a01;
        u0.z = hiSel ? b10 : b00;  u0.w = hiSel ? b11 : b01;
        u1.x = hiSel ? a30 : a20;  u1.y = hiSel ? a31 : a21;
        u1.z = hiSel ? b30 : b20;  u1.w = hiSel ? b31 : b21;
        pa0 = *(bf16x8*)&u0;
        pa1 = *(bf16x8*)&u1;
    };
    auto strip_pass2 = [&](int cur, int qrow, int kt, float m_f, float linv,
                           bf16x8 qa, bf16x8 qb, f32x4* accj) {
        f32x4 s[4];
        qk_tile(cur, qa, qb, s);
        float pv[4][4];
#pragma unroll
        for (int kk = 0; kk < 4; ++kk) {
#pragma unroll
            for (int r = 0; r < 4; ++r) {
                const int key = kt * 64 + kk * 16 + hi * 4 + r;
                pv[kk][r] = (key <= qrow) ? __expf(s[kk][r] * 0.125f - m_f) * linv : 0.f;
            }
            float4 st;
            st.x = pv[kk][0]; st.y = pv[kk][1]; st.z = pv[kk][2]; st.w = pv[kk][3];
            *(float4*)&attn_h[(size_t)qrow * SEQ + kt * 64 + kk * 16 + hi * 4] = st;
        }
        bf16x8 pa0, pa1;
        exchange(pv, pa0, pa1);
#pragma unroll
        for (int jt = 0; jt < 4; ++jt) {
            const char* vbp = (const char*)&Vs[cur][0] + (jt * 16 + l15) * 128;
            bf16x8 v0 = *(const bf16x8*)(vbp + ((hi * 16) ^ swz));
            bf16x8 v1 = *(const bf16x8*)(vbp + ((64 + hi * 16) ^ swz));
            accj[jt] = __builtin_amdgcn_mfma_f32_16x16x32_bf16(pa0, v0, accj[jt], 0, 0, 0);
            accj[jt] = __builtin_amdgcn_mfma_f32_16x16x32_bf16(pa1, v1, accj[jt], 0, 0, 0);
        }
    };

    stageK(0, 0);
    stageV(0, 0);
    __syncthreads();
    cur = 0;
    for (int kt = 0; kt <= qtb; ++kt) {
        if (kt < qtb) { stageK(cur ^ 1, kt + 1); stageV(cur ^ 1, kt + 1); }
        if (kt < qtb) strip_pass2(cur, qr0, kt, m0f, l0inv, qa0, qb0, acc0);
        strip_pass2(cur, qr1, kt, m1f, l1inv, qa1, qb1, acc1);
        __syncthreads();   // implicit vmcnt(0): next K/V staged; reads of cur done
        cur ^= 1;
    }

    // zero-fill masked upper tiles: strip0 from kt=qtb, strip1 from kt=qtb+1
    const float4 zf = make_float4(0.f, 0.f, 0.f, 0.f);
    for (int kt = qtb; kt < SEQ / 64; ++kt) {
#pragma unroll
        for (int kk = 0; kk < 4; ++kk)
            *(float4*)&attn_h[(size_t)qr0 * SEQ + kt * 64 + kk * 16 + hi * 4] = zf;
    }
    for (int kt = qtb + 1; kt < SEQ / 64; ++kt) {
#pragma unroll
        for (int kk = 0; kk < 4; ++kk)
            *(float4*)&attn_h[(size_t)qr1 * SEQ + kt * 64 + kk * 16 + hi * 4] = zf;
    }

    // ctx write (bf16, B,S,D layout): lane holds ctx[q=base+hi*4+r][d=jt*16+l15]
#pragma unroll
    for (int jt = 0; jt < 4; ++jt) {
        const int d = jt * 16 + l15;
#pragma unroll
        for (int r = 0; r < 4; ++r) {
            const int qq0 = q0 + w * 16 + hi * 4 + r;
            ctx_h[(size_t)qq0 * D_MODEL + d] = f2bf(acc0[jt][r]);
            ctx_h[(size_t)(qq0 + 64) * D_MODEL + d] = f2bf(acc1[jt][r]);
        }
    }
}

// ---------------------------------------------------------------------------
extern "C" void kernel_launch(void* const* d_in, const int* in_sizes, int n_in,
                              void* d_out, int out_size, void* d_ws, size_t ws_size,
                              hipStream_t stream)
{
    const float* q  = (const float*)d_in[0];
    const float* k  = (const float*)d_in[1];
    const float* v  = (const float*)d_in[2];
    const float* wq = (const float*)d_in[4];
    const float* bq = (const float*)d_in[5];
    const float* wk = (const float*)d_in[6];
    const float* bk = (const float*)d_in[7];
    const float* wv = (const float*)d_in[8];
    const float* bv = (const float*)d_in[9];
    const float* wo = (const float*)d_in[10];
    const float* bo = (const float*)d_in[11];

    float* out  = (float*)d_out;
    float* attn = out + (size_t)BATCH * SEQ * D_MODEL;

    const size_t NE = (size_t)MTOT * D_MODEL;     // 4194304
    const size_t WE = (size_t)D_MODEL * D_MODEL;  // 1048576
    unsigned short* ws  = (unsigned short*)d_ws;
    unsigned short* qb  = ws;
    unsigned short* kb  = qb + NE;
    unsigned short* vb  = kb + NE;
    unsigned short* wT  = vb + NE;                // 4 slabs: wq,wk,wv,wo transposed
    unsigned short* Qp  = wT + 4 * WE;            // (B,H,S,64) bf16
    unsigned short* Kp  = Qp + NE;
    unsigned short* Vt  = Kp + NE;                // (B,H,64,S) bf16 (transposed!)
    unsigned short* ctxb = Vt + NE;               // (B,S,D) bf16

    const int n4 = (int)(NE / 4);
    cast3_f32_bf16<<<dim3((n4 + 255) / 256, 3), 256, 0, stream>>>(q, k, v, qb, n4);
    transpose_cast_w<<<dim3(32, 32, 4), 256, 0, stream>>>(wq, wk, wv, wo, wT);

    gemm_mfma<0><<<dim3(32, 8, 3), 256, 0, stream>>>(qb, kb, vb, wT, bq, bk, bv,
                                                     Qp, Kp, Vt, nullptr);

    dim3 ga(SEQ / 128, BATCH * NH);
    attn_fused<<<ga, 256, 0, stream>>>(Qp, Kp, Vt, attn, ctxb);

    gemm_mfma<1><<<dim3(32, 16, 1), 256, 0, stream>>>(ctxb, nullptr, nullptr, wT + 3 * WE,
                                                      bo, nullptr, nullptr,
                                                      nullptr, nullptr, nullptr, out);
}